// Round 11
// baseline (2433.086 us; speedup 1.0000x reference)
//
#include <hip/hip_runtime.h>

#define T_DIM 128
#define B_DIM 256
#define H_DIM 1024
#define E_DIM 1024
#define Z_DIM 512

typedef __attribute__((ext_vector_type(8))) short short8;
typedef __attribute__((ext_vector_type(4))) float f32x4;
typedef __attribute__((ext_vector_type(4))) unsigned short u16x4;

__device__ __forceinline__ unsigned short f2bf(float f) {
  unsigned u = __float_as_uint(f);
  u += 0x7fffu + ((u >> 16) & 1u);   // round-to-nearest-even
  return (unsigned short)(u >> 16);
}
__device__ __forceinline__ float sigf(float x) { return 1.0f / (1.0f + __expf(-x)); }
__device__ __forceinline__ float tanhf_(float x) { return 2.0f * sigf(2.0f * x) - 1.0f; }

// global -> LDS direct copy, 16B per lane
__device__ __forceinline__ void async16(const void* g, void* lds) {
  auto gp = (const __attribute__((address_space(1))) unsigned int*)((unsigned long long)g);
  auto lp = (__attribute__((address_space(3))) unsigned int*)((unsigned int)(unsigned long long)lds);
  __builtin_amdgcn_global_load_lds(gp, lp, 16, 0, 0);
}

// ---------------- prep kernels (verified rounds 1-10) ----------------

__global__ void cvt_wr(const float* __restrict__ p0, const float* __restrict__ p1,
                       const float* __restrict__ p2, const float* __restrict__ p3,
                       unsigned short* __restrict__ out) {
  size_t i = (size_t)blockIdx.x * 256 + threadIdx.x;
  const float* in = blockIdx.y == 0 ? p0 : blockIdx.y == 1 ? p1 : blockIdx.y == 2 ? p2 : p3;
  out[(size_t)blockIdx.y * (H_DIM * H_DIM) + i] = f2bf(in[i]);
}

__global__ void transpose_k(const float* __restrict__ p0, const float* __restrict__ p1,
                            const float* __restrict__ p2, const float* __restrict__ p3,
                            unsigned short* __restrict__ out, int K, int N) {
  const float* in = blockIdx.z == 0 ? p0 : blockIdx.z == 1 ? p1 : blockIdx.z == 2 ? p2 : p3;
  unsigned short* o = out + (size_t)blockIdx.z * K * N;
  __shared__ float tile[32][33];
  int n0 = blockIdx.x * 32;
  int k0 = blockIdx.y * 32;
#pragma unroll
  for (int i = threadIdx.y; i < 32; i += 8)
    tile[i][threadIdx.x] = in[(size_t)(k0 + i) * N + (n0 + threadIdx.x)];
  __syncthreads();
#pragma unroll
  for (int i = threadIdx.y; i < 32; i += 8)
    o[(size_t)(n0 + i) * K + (k0 + threadIdx.x)] = f2bf(tile[threadIdx.x][i]);
}

__global__ void init_state(const float* __restrict__ hidden, const float* __restrict__ cell,
                           const float* __restrict__ bi, const float* __restrict__ bf,
                           const float* __restrict__ bo, const float* __restrict__ bl,
                           const float* __restrict__ bz, const float* __restrict__ bc,
                           unsigned short* __restrict__ h0, float* __restrict__ c0,
                           float* __restrict__ bias, unsigned* __restrict__ counter) {
  int i = blockIdx.x * 256 + threadIdx.x;
  const int BH = B_DIM * H_DIM;
  if (i < BH) { h0[i] = f2bf(hidden[i]); return; }
  int j = i - BH;
  if (j < BH) { c0[j] = cell[j]; return; }
  int k = j - BH;
  if (k < 6 * H_DIM) {
    int p = k / H_DIM, q = k - p * H_DIM;
    const float* src = p == 0 ? bi : p == 1 ? bf : p == 2 ? bo : p == 3 ? bc : p == 4 ? bl : bz;
    bias[k] = src[q];
    return;
  }
  int k2 = k - 6 * H_DIM;
  if (k2 < 256) counter[k2] = 0;   // barrier counters reset (every call/replay)
}

// f32 -> bf16, 4 elems/thread
__global__ void cvt_bf16x4(const float* __restrict__ in, unsigned short* __restrict__ out, int n4) {
  int i = blockIdx.x * 256 + threadIdx.x;
  if (i >= n4) return;
  f32x4 v = ((const f32x4*)in)[i];
  u16x4 o;
#pragma unroll
  for (int j = 0; j < 4; ++j) o[j] = f2bf(v[j]);
  ((u16x4*)out)[i] = o;
}

// ---------------- Phase A: unified B^T GEMM (m97-style LDS staging) ----------------
__global__ __launch_bounds__(256) void gemm_bt(
    const unsigned short* __restrict__ A, const unsigned short* __restrict__ B,
    const float* __restrict__ bias, float* __restrict__ P, size_t pstride, int K) {
  __shared__ unsigned short As[128 * 64];
  __shared__ unsigned short Bs[128 * 64];
  unsigned nwg = gridDim.x * gridDim.y;
  unsigned bid = blockIdx.y * gridDim.x + blockIdx.x;
  unsigned swz = (bid & 7) * (nwg >> 3) + (bid >> 3);
  const int bx = swz % gridDim.x, by = swz / gridDim.x;
  const int m0 = by * 128, n0 = bx * 128;
  const int tid = threadIdx.x;
  const int lane = tid & 63, wv = tid >> 6;
  const int lr = lane & 15, lg = lane >> 4;
  const int m_wave = (wv >> 1) * 64, n_wave = (wv & 1) * 64;

  f32x4 acc[4][4] = {};
  const int nk = K >> 6;
  const int srow = tid >> 3, skc = tid & 7;
  for (int ks = 0; ks < nk; ++ks) {
#pragma unroll
    for (int it = 0; it < 4; ++it) {
      int row = it * 32 + srow;
      unsigned ldsoff = (unsigned)(it * 4096 + (tid >> 6) * 1024);
      async16(A + (size_t)(m0 + row) * K + ks * 64 + skc * 8, (char*)As + ldsoff);
      async16(B + (size_t)(n0 + row) * K + ks * 64 + skc * 8, (char*)Bs + ldsoff);
    }
    __syncthreads();
#pragma unroll
    for (int kk = 0; kk < 64; kk += 32) {
      short8 a[4], b[4];
#pragma unroll
      for (int i = 0; i < 4; ++i)
        a[i] = *(const short8*)(As + (m_wave + i * 16 + lr) * 64 + kk + lg * 8);
#pragma unroll
      for (int i = 0; i < 4; ++i)
        b[i] = *(const short8*)(Bs + (n_wave + i * 16 + lr) * 64 + kk + lg * 8);
#pragma unroll
      for (int mi = 0; mi < 4; ++mi)
#pragma unroll
        for (int ni = 0; ni < 4; ++ni)
          acc[mi][ni] = __builtin_amdgcn_mfma_f32_16x16x32_bf16(a[mi], b[ni], acc[mi][ni], 0, 0, 0);
    }
    __syncthreads();
  }
#pragma unroll
  for (int ni = 0; ni < 4; ++ni) {
    int ng = n0 + n_wave + ni * 16 + lr;
    float bv = bias[ng];
    float* outp = P + (size_t)(ng >> 10) * pstride + (ng & 1023);
#pragma unroll
    for (int mi = 0; mi < 4; ++mi)
#pragma unroll
      for (int j = 0; j < 4; ++j) {
        int m = m0 + m_wave + mi * 16 + lg * 4 + j;
        outp[(size_t)m * 1024] = acc[mi][ni][j] + bv;
      }
  }
}

// ---------------- Phase B: persistent recurrent scan (R8-validated structure) ----------------
// 256 blocks x 512 threads (8 waves). Block: n-slice 16 cols (4 planes, K=1024 in LDS),
// m-slice 64 batch rows. Wave w: ph=w&1 (plane pair), kh=(w>>1)&1 (K half), mh=w>>2.
// Coherence (validated R8/R10): h stores write-through L3 (sc0 sc1), h loads cached,
// freshness via one ACQUIRE (L1/L2 inv) after spin-detect. All stores drained by the
// pre-arrival vmcnt(0)+__syncthreads BEFORE the arrival add — do not reorder (R9's
// out-store-after-arrival variant failed replay re-validation).
// New in R11 (pure index permutation): XCD-confined m-groups. Dispatch round-robins
// bid%8 across XCDs, so mapping mg=(bid&7)>>1 puts each m-group's 64 blocks on
// exactly 2 XCDs: after the acquire-invalidate each XCD refills ONE group's 128KB
// h-slice from L3 (was 4 slices), 32 blocks share each L2 fill (was 8), and the
// barrier counter line is polled from 2 dies instead of 8.
__global__ __launch_bounds__(512) void lstm_scan(
    int t0, int tc, const unsigned short* __restrict__ Wr,
    const float* __restrict__ P, size_t pstride,
    unsigned short* __restrict__ hbuf0, unsigned short* __restrict__ hbuf1,
    const float* __restrict__ cell, float* __restrict__ cbuf,
    float* __restrict__ out, unsigned* __restrict__ counter) {
  __shared__ unsigned short Wsm[4 * 16 * 1024];  // 128 KB
  __shared__ float fin[4][64][18];               // 18.4 KB exchange buffer

  const int tid = threadIdx.x;
  const int lane = tid & 63, w = tid >> 6;
  const int lr = lane & 15, lg = lane >> 4;
  const int ph = w & 1, kh = (w >> 1) & 1, mh = w >> 2;
  // XCD-confined remap: m-group from XCD bits, n-slice from the rest (bijective).
  const int bid = blockIdx.x;
  const int mg = (bid & 7) >> 1;                    // m-group 0..3 -> XCDs {2g,2g+1}
  const int ns = ((bid >> 3) << 1) | (bid & 1);     // n-slice 0..63
  const int n0 = ns * 16, m0 = mg * 64;
  unsigned* cnt = counter + mg * 64;                // per-m-group arrival line

  // stage Wr slice into LDS (once): row r = p*16+c holds W[p][n0+c][0..1023]
  for (int id = tid; id < 8192; id += 512) {
    int r = id >> 7, s = id & 127;
    int p = r >> 4, c = r & 15;
    short8 v = *(const short8*)(Wr + ((size_t)p * H_DIM + n0 + c) * H_DIM + s * 8);
    *(short8*)((char*)Wsm + r * 2048 + ((s ^ (c & 7)) << 4)) = v;
  }

  // per-thread epilogue ownership: 2 consecutive elements of the 64x16 tile
  const int em = tid >> 3, en = (tid & 7) * 2;
  const size_t cidx = (size_t)(m0 + em) * H_DIM + n0 + en;
  float creg0, creg1;
  {
    const float* csrc = (t0 == 0) ? cell : cbuf;
    creg0 = csrc[cidx];
    creg1 = csrc[cidx + 1];
  }
  __syncthreads();

  const int p0 = ph * 2;
  const int brow0 = (p0 * 16 + lr) * 2048, brow1 = brow0 + 16 * 2048;
  const int swz = (lr & 7) << 4;
  const size_t arow_off = (size_t)(m0 + mh * 32 + lr) * H_DIM + kh * 512 + lg * 8;

  // preload gate pre-acts for tmod=0 (P is a stable, read-only input)
  float pv[6][2];
  {
    const float* Pe = P + cidx;
#pragma unroll
    for (int p = 0; p < 6; ++p) {
      pv[p][0] = Pe[p * pstride];
      pv[p][1] = Pe[p * pstride + 1];
    }
  }

  for (int tmod = 0; tmod < tc; ++tmod) {
    const int t = t0 + tmod;
    const unsigned short* hin = (t & 1) ? hbuf1 : hbuf0;
    unsigned short* hout = (t & 1) ? hbuf0 : hbuf1;

    // batched cached A loads: full K-half for 2 rows (32 x 16B into regs).
    // Fresh because the barrier's ACQUIRE invalidated L1/L2; 32 same-group
    // blocks per XCD share the L3->L2 fill.
    short8 h0r[16], h1r[16];
    {
      const unsigned short* a0p = hin + arow_off;
      const unsigned short* a1p = a0p + 16 * H_DIM;
#pragma unroll
      for (int ki = 0; ki < 16; ++ki) {
        h0r[ki] = *(const short8*)(a0p + ki * 32);
        h1r[ki] = *(const short8*)(a1p + ki * 32);
      }
    }

    f32x4 acc[2][2] = {};  // [plane-in-pair][m-tile]
#pragma unroll
    for (int ki = 0; ki < 16; ++ki) {
      int sb = ((kh * 64 + ki * 4 + lg) << 4) ^ swz;
      short8 b0 = *(const short8*)((char*)Wsm + brow0 + sb);
      short8 b1 = *(const short8*)((char*)Wsm + brow1 + sb);
      acc[0][0] = __builtin_amdgcn_mfma_f32_16x16x32_bf16(h0r[ki], b0, acc[0][0], 0, 0, 0);
      acc[0][1] = __builtin_amdgcn_mfma_f32_16x16x32_bf16(h1r[ki], b0, acc[0][1], 0, 0, 0);
      acc[1][0] = __builtin_amdgcn_mfma_f32_16x16x32_bf16(h0r[ki], b1, acc[1][0], 0, 0, 0);
      acc[1][1] = __builtin_amdgcn_mfma_f32_16x16x32_bf16(h1r[ki], b1, acc[1][1], 0, 0, 0);
    }

    // prefetch next step's P into registers (overlaps LDS exchange + barrier)
    float pn[6][2] = {};
    if (tmod + 1 < tc) {
      const float* Pe = P + (size_t)(tmod + 1) * (B_DIM * H_DIM) + cidx;
#pragma unroll
      for (int p = 0; p < 6; ++p) {
        pn[p][0] = Pe[p * pstride];
        pn[p][1] = Pe[p * pstride + 1];
      }
    }

    // phase 1: kh=1 waves publish partials
    if (kh == 1) {
#pragma unroll
      for (int pp = 0; pp < 2; ++pp)
#pragma unroll
        for (int i = 0; i < 2; ++i)
#pragma unroll
          for (int j = 0; j < 4; ++j)
            fin[p0 + pp][mh * 32 + i * 16 + lg * 4 + j][lr] = acc[pp][i][j];
    }
    __syncthreads();

    // phase 2: kh=0 waves reduce and publish all 4 planes
    if (kh == 0) {
#pragma unroll
      for (int pp = 0; pp < 2; ++pp)
#pragma unroll
        for (int i = 0; i < 2; ++i)
#pragma unroll
          for (int j = 0; j < 4; ++j) {
            int mrow = mh * 32 + i * 16 + lg * 4 + j;
            fin[p0 + pp][mrow][lr] = acc[pp][i][j] + fin[p0 + pp][mrow][lr];
          }
    }
    __syncthreads();

    // phase 3: balanced epilogue — every thread handles its 2 elements
    {
      float r0a = fin[0][em][en], r0b = fin[0][em][en + 1];
      float r1a = fin[1][em][en], r1b = fin[1][em][en + 1];
      float r2a = fin[2][em][en], r2b = fin[2][em][en + 1];
      float r3a = fin[3][em][en], r3b = fin[3][em][en + 1];

      float ig0 = sigf(r0a + pv[0][0]), ig1 = sigf(r0b + pv[0][1]);
      float fg0 = sigf(r1a + pv[1][0]), fg1 = sigf(r1b + pv[1][1]);
      float og0 = sigf(r2a + pv[2][0]), og1 = sigf(r2b + pv[2][1]);
      float ct0 = tanhf_(r3a + pv[3][0]), ct1 = tanhf_(r3b + pv[3][1]);
      float lz0 = sigf(pv[4][0]) * tanhf_(pv[5][0]);
      float lz1 = sigf(pv[4][1]) * tanhf_(pv[5][1]);
      creg0 = fg0 * creg0 + ig0 * ct0 + lz0;
      creg1 = fg1 * creg1 + ig1 * ct1 + lz1;
      float hn0 = og0 * tanhf_(creg0);
      float hn1 = og1 * tanhf_(creg1);
      // h store: write-through to L3 (sc0 sc1) so no wbl2 fence is needed
      unsigned hv = (unsigned)f2bf(hn0) | ((unsigned)f2bf(hn1) << 16);
      asm volatile("global_store_dword %0, %1, off sc0 sc1"
                   :: "v"(hout + cidx), "v"(hv) : "memory");
      float* op = out + (size_t)t * (B_DIM * H_DIM) + cidx;
      __builtin_nontemporal_store(hn0, op);
      __builtin_nontemporal_store(hn1, op + 1);
    }

    // per-m-group barrier: drain stores, relaxed arrival, relaxed spin,
    // then ONE acquire load (L1/L2 invalidate) so next h loads are fresh.
    asm volatile("s_waitcnt vmcnt(0)" ::: "memory");
    __syncthreads();
    if (tid == 0) {
      __hip_atomic_fetch_add(cnt, 1u, __ATOMIC_RELAXED, __HIP_MEMORY_SCOPE_AGENT);
      if (tmod + 1 < tc) {   // last step: arrival only (keeps absolute count valid)
        unsigned tgt = 64u * (unsigned)(t + 1);
        while (__hip_atomic_load(cnt, __ATOMIC_RELAXED, __HIP_MEMORY_SCOPE_AGENT) < tgt)
          __builtin_amdgcn_s_sleep(1);
        (void)__hip_atomic_load(cnt, __ATOMIC_ACQUIRE, __HIP_MEMORY_SCOPE_AGENT);
      }
    }
    __syncthreads();

    // rotate prefetched P
#pragma unroll
    for (int p = 0; p < 6; ++p) {
      pv[p][0] = pn[p][0];
      pv[p][1] = pn[p][1];
    }
  }

  // spill c for the next chunk (kernel-end release makes it visible)
  cbuf[cidx] = creg0;
  cbuf[cidx + 1] = creg1;
}

// ---------------- fallback fused step (round-1, verified) ----------------
__global__ __launch_bounds__(256) void lstm_step(
    int t, const float* __restrict__ x, const float* __restrict__ z,
    const unsigned short* __restrict__ Wr, const unsigned short* __restrict__ Wx,
    const unsigned short* __restrict__ Wz, const float* __restrict__ bias,
    const unsigned short* __restrict__ hin, unsigned short* __restrict__ hout,
    float* __restrict__ cbuf, float* __restrict__ out) {
  const int lane = threadIdx.x & 63;
  const int wv = threadIdx.x >> 6;
  const int m_base = blockIdx.y * 16;
  const int n_base = blockIdx.x * 64 + wv * 16;
  const int lr = lane & 15;
  const int lg = lane >> 4;
  const int n = n_base + lr;

  f32x4 acc[6];
#pragma unroll
  for (int p = 0; p < 6; ++p) {
    float bv = bias[p * H_DIM + n];
    acc[p] = (f32x4){bv, bv, bv, bv};
  }
  const unsigned short* hrow = hin + (size_t)(m_base + lr) * H_DIM + lg * 8;
  const float* xrow = x + ((size_t)t * B_DIM + m_base + lr) * E_DIM + lg * 8;
  const float* zrow = z + ((size_t)t * B_DIM + m_base + lr) * Z_DIM + lg * 8;
  const unsigned short* wrp = Wr + (size_t)n * H_DIM + lg * 8;
  const unsigned short* wxp = Wx + (size_t)n * E_DIM + lg * 8;
  const unsigned short* wzp = Wz + (size_t)n * Z_DIM + lg * 8;

#pragma unroll 2
  for (int kk = 0; kk < H_DIM; kk += 32) {
    short8 a = *(const short8*)(hrow + kk);
    short8 b0 = *(const short8*)(wrp + kk);
    short8 b1 = *(const short8*)(wrp + 1 * H_DIM * H_DIM + kk);
    short8 b2 = *(const short8*)(wrp + 2 * H_DIM * H_DIM + kk);
    short8 b3 = *(const short8*)(wrp + 3 * H_DIM * H_DIM + kk);
    acc[0] = __builtin_amdgcn_mfma_f32_16x16x32_bf16(a, b0, acc[0], 0, 0, 0);
    acc[1] = __builtin_amdgcn_mfma_f32_16x16x32_bf16(a, b1, acc[1], 0, 0, 0);
    acc[2] = __builtin_amdgcn_mfma_f32_16x16x32_bf16(a, b2, acc[2], 0, 0, 0);
    acc[3] = __builtin_amdgcn_mfma_f32_16x16x32_bf16(a, b3, acc[3], 0, 0, 0);
  }
#pragma unroll 2
  for (int kk = 0; kk < E_DIM; kk += 32) {
    f32x4 x0 = *(const f32x4*)(xrow + kk);
    f32x4 x1 = *(const f32x4*)(xrow + kk + 4);
    short8 a;
#pragma unroll
    for (int j = 0; j < 4; ++j) { a[j] = (short)f2bf(x0[j]); a[j + 4] = (short)f2bf(x1[j]); }
    short8 b0 = *(const short8*)(wxp + kk);
    short8 b1 = *(const short8*)(wxp + 1 * H_DIM * E_DIM + kk);
    short8 b2 = *(const short8*)(wxp + 2 * H_DIM * E_DIM + kk);
    short8 b3 = *(const short8*)(wxp + 3 * H_DIM * E_DIM + kk);
    acc[0] = __builtin_amdgcn_mfma_f32_16x16x32_bf16(a, b0, acc[0], 0, 0, 0);
    acc[1] = __builtin_amdgcn_mfma_f32_16x16x32_bf16(a, b1, acc[1], 0, 0, 0);
    acc[2] = __builtin_amdgcn_mfma_f32_16x16x32_bf16(a, b2, acc[2], 0, 0, 0);
    acc[3] = __builtin_amdgcn_mfma_f32_16x16x32_bf16(a, b3, acc[3], 0, 0, 0);
  }
#pragma unroll 2
  for (int kk = 0; kk < Z_DIM; kk += 32) {
    f32x4 z0 = *(const f32x4*)(zrow + kk);
    f32x4 z1 = *(const f32x4*)(zrow + kk + 4);
    short8 a;
#pragma unroll
    for (int j = 0; j < 4; ++j) { a[j] = (short)f2bf(z0[j]); a[j + 4] = (short)f2bf(z1[j]); }
    short8 b4 = *(const short8*)(wzp + kk);
    short8 b5 = *(const short8*)(wzp + 1 * H_DIM * Z_DIM + kk);
    acc[4] = __builtin_amdgcn_mfma_f32_16x16x32_bf16(a, b4, acc[4], 0, 0, 0);
    acc[5] = __builtin_amdgcn_mfma_f32_16x16x32_bf16(a, b5, acc[5], 0, 0, 0);
  }
#pragma unroll
  for (int j = 0; j < 4; ++j) {
    int b = m_base + lg * 4 + j;
    size_t idx = (size_t)b * H_DIM + n;
    float ig = sigf(acc[0][j]);
    float fg = sigf(acc[1][j]);
    float og = sigf(acc[2][j]);
    float ct = tanhf_(acc[3][j]);
    float lgate = sigf(acc[4][j]);
    float zh = tanhf_(acc[5][j]);
    float cn = fg * cbuf[idx] + ig * ct + lgate * zh;
    cbuf[idx] = cn;
    float hn = og * tanhf_(cn);
    hout[idx] = f2bf(hn);
    out[(size_t)t * (B_DIM * H_DIM) + idx] = hn;
  }
}

// ---------------- launch ----------------

extern "C" void kernel_launch(void* const* d_in, const int* in_sizes, int n_in,
                              void* d_out, int out_size, void* d_ws, size_t ws_size,
                              hipStream_t stream) {
  const float* x = (const float*)d_in[0];
  const float* z = (const float*)d_in[1];
  const float* hidden = (const float*)d_in[2];
  const float* cell = (const float*)d_in[3];
  const float* w_ih = (const float*)d_in[4];
  const float* w_oh = (const float*)d_in[5];
  const float* w_fh = (const float*)d_in[6];
  const float* w_ch = (const float*)d_in[7];
  const float* w_ix = (const float*)d_in[8];
  const float* w_ox = (const float*)d_in[9];
  const float* w_fx = (const float*)d_in[10];
  const float* w_cx = (const float*)d_in[11];
  const float* w_lx = (const float*)d_in[12];
  const float* w_zx = (const float*)d_in[13];
  const float* b_i = (const float*)d_in[14];
  const float* b_f = (const float*)d_in[15];
  const float* b_o = (const float*)d_in[16];
  const float* b_l = (const float*)d_in[17];
  const float* b_z = (const float*)d_in[18];
  const float* b_c = (const float*)d_in[19];

  char* ws = (char*)d_ws;
  unsigned short* Wr = (unsigned short*)(ws + 0);          //  8 MB [4][1024][1024]
  unsigned short* Wx = (unsigned short*)(ws + 8388608);    //  8 MB [4][1024][1024]
  unsigned short* Wz = (unsigned short*)(ws + 16777216);   //  2 MB [2][1024][512]
  float* bias = (float*)(ws + 18874368);                   // 24 KB [6][1024]
  unsigned short* h0 = (unsigned short*)(ws + 18898944);   // 512 KB
  unsigned short* h1 = (unsigned short*)(ws + 19423232);   // 512 KB
  float* cbuf = (float*)(ws + 19947520);                   //   1 MB
  unsigned* counter = (unsigned*)(ws + 20996096);          //   1 KB (4 counters, 256B apart)
  float* out = (float*)d_out;

  const size_t FIXED = 20997120ULL;
  const size_t PER_T = 7077888ULL;  // xbf 512K + zbf 256K + P[6 planes] 6M
  int TC = 0;
  for (int c = 128; c >= 1; c >>= 1)
    if (FIXED + (size_t)c * PER_T <= ws_size) { TC = c; break; }

  // shared prep
  cvt_wr<<<dim3(4096, 4), 256, 0, stream>>>(w_ih, w_fh, w_oh, w_ch, Wr);
  transpose_k<<<dim3(32, 32, 4), dim3(32, 8), 0, stream>>>(w_ix, w_fx, w_ox, w_cx, Wx, E_DIM, H_DIM);
  transpose_k<<<dim3(32, 16, 2), dim3(32, 8), 0, stream>>>(w_lx, w_zx, w_lx, w_zx, Wz, Z_DIM, H_DIM);
  init_state<<<2074, 256, 0, stream>>>(hidden, cell, b_i, b_f, b_o, b_l, b_z, b_c, h0, cbuf, bias, counter);

  if (TC > 0) {
    unsigned short* xbf = (unsigned short*)(ws + FIXED);
    unsigned short* zbf = (unsigned short*)(ws + FIXED + (size_t)TC * 524288);
    float* P = (float*)(ws + FIXED + (size_t)TC * 786432);
    const size_t pstride = (size_t)TC * B_DIM * H_DIM;

    for (int t0 = 0; t0 < T_DIM; t0 += TC) {
      int nx4 = TC * B_DIM * E_DIM / 4;
      int nz4 = TC * B_DIM * Z_DIM / 4;
      cvt_bf16x4<<<(nx4 + 255) / 256, 256, 0, stream>>>(x + (size_t)t0 * B_DIM * E_DIM, xbf, nx4);
      cvt_bf16x4<<<(nz4 + 255) / 256, 256, 0, stream>>>(z + (size_t)t0 * B_DIM * Z_DIM, zbf, nz4);
      gemm_bt<<<dim3(32, TC * 2), 256, 0, stream>>>(xbf, Wx, bias, P, pstride, E_DIM);
      gemm_bt<<<dim3(16, TC * 2), 256, 0, stream>>>(zbf, Wz, bias + 4 * H_DIM, P + 4 * pstride, pstride, Z_DIM);
      lstm_scan<<<256, 512, 0, stream>>>(t0, TC, Wr, P, pstride, h0, h1, cell, cbuf, out, counter);
    }
  } else {
    // fallback: fully fused per-step path (round 1, verified)
    for (int t = 0; t < T_DIM; ++t) {
      const unsigned short* hin = (t & 1) ? h1 : h0;
      unsigned short* hout = (t & 1) ? h0 : h1;
      lstm_step<<<dim3(16, 16), 256, 0, stream>>>(t, x, z, Wr, Wx, Wz, bias, hin, hout, cbuf, out);
    }
  }
}

// Round 12
// 2263.633 us; speedup vs baseline: 1.0749x; 1.0749x over previous
//
#include <hip/hip_runtime.h>

#define T_DIM 128
#define B_DIM 256
#define H_DIM 1024
#define E_DIM 1024
#define Z_DIM 512

typedef __attribute__((ext_vector_type(8))) short short8;
typedef __attribute__((ext_vector_type(4))) float f32x4;
typedef __attribute__((ext_vector_type(4))) unsigned short u16x4;

__device__ __forceinline__ unsigned short f2bf(float f) {
  unsigned u = __float_as_uint(f);
  u += 0x7fffu + ((u >> 16) & 1u);   // round-to-nearest-even
  return (unsigned short)(u >> 16);
}
__device__ __forceinline__ float sigf(float x) { return 1.0f / (1.0f + __expf(-x)); }
__device__ __forceinline__ float tanhf_(float x) { return 2.0f * sigf(2.0f * x) - 1.0f; }

// global -> LDS direct copy, 16B per lane
__device__ __forceinline__ void async16(const void* g, void* lds) {
  auto gp = (const __attribute__((address_space(1))) unsigned int*)((unsigned long long)g);
  auto lp = (__attribute__((address_space(3))) unsigned int*)((unsigned int)(unsigned long long)lds);
  __builtin_amdgcn_global_load_lds(gp, lp, 16, 0, 0);
}

// ---------------- prep kernels (verified rounds 1-11) ----------------

__global__ void cvt_wr(const float* __restrict__ p0, const float* __restrict__ p1,
                       const float* __restrict__ p2, const float* __restrict__ p3,
                       unsigned short* __restrict__ out) {
  size_t i = (size_t)blockIdx.x * 256 + threadIdx.x;
  const float* in = blockIdx.y == 0 ? p0 : blockIdx.y == 1 ? p1 : blockIdx.y == 2 ? p2 : p3;
  out[(size_t)blockIdx.y * (H_DIM * H_DIM) + i] = f2bf(in[i]);
}

__global__ void transpose_k(const float* __restrict__ p0, const float* __restrict__ p1,
                            const float* __restrict__ p2, const float* __restrict__ p3,
                            unsigned short* __restrict__ out, int K, int N) {
  const float* in = blockIdx.z == 0 ? p0 : blockIdx.z == 1 ? p1 : blockIdx.z == 2 ? p2 : p3;
  unsigned short* o = out + (size_t)blockIdx.z * K * N;
  __shared__ float tile[32][33];
  int n0 = blockIdx.x * 32;
  int k0 = blockIdx.y * 32;
#pragma unroll
  for (int i = threadIdx.y; i < 32; i += 8)
    tile[i][threadIdx.x] = in[(size_t)(k0 + i) * N + (n0 + threadIdx.x)];
  __syncthreads();
#pragma unroll
  for (int i = threadIdx.y; i < 32; i += 8)
    o[(size_t)(n0 + i) * K + (k0 + threadIdx.x)] = f2bf(tile[threadIdx.x][i]);
}

__global__ void init_state(const float* __restrict__ hidden, const float* __restrict__ cell,
                           const float* __restrict__ bi, const float* __restrict__ bf,
                           const float* __restrict__ bo, const float* __restrict__ bl,
                           const float* __restrict__ bz, const float* __restrict__ bc,
                           unsigned short* __restrict__ h0, float* __restrict__ c0,
                           float* __restrict__ bias, unsigned* __restrict__ counter) {
  int i = blockIdx.x * 256 + threadIdx.x;
  const int BH = B_DIM * H_DIM;
  if (i < BH) { h0[i] = f2bf(hidden[i]); return; }
  int j = i - BH;
  if (j < BH) { c0[j] = cell[j]; return; }
  int k = j - BH;
  if (k < 6 * H_DIM) {
    int p = k / H_DIM, q = k - p * H_DIM;
    const float* src = p == 0 ? bi : p == 1 ? bf : p == 2 ? bo : p == 3 ? bc : p == 4 ? bl : bz;
    bias[k] = src[q];
    return;
  }
  int k2 = k - 6 * H_DIM;
  if (k2 < 256) counter[k2] = 0;   // cnt/go lines reset (every call/replay)
}

// f32 -> bf16, 4 elems/thread
__global__ void cvt_bf16x4(const float* __restrict__ in, unsigned short* __restrict__ out, int n4) {
  int i = blockIdx.x * 256 + threadIdx.x;
  if (i >= n4) return;
  f32x4 v = ((const f32x4*)in)[i];
  u16x4 o;
#pragma unroll
  for (int j = 0; j < 4; ++j) o[j] = f2bf(v[j]);
  ((u16x4*)out)[i] = o;
}

// ---------------- Phase A: unified B^T GEMM (m97-style LDS staging) ----------------
__global__ __launch_bounds__(256) void gemm_bt(
    const unsigned short* __restrict__ A, const unsigned short* __restrict__ B,
    const float* __restrict__ bias, float* __restrict__ P, size_t pstride, int K) {
  __shared__ unsigned short As[128 * 64];
  __shared__ unsigned short Bs[128 * 64];
  unsigned nwg = gridDim.x * gridDim.y;
  unsigned bid = blockIdx.y * gridDim.x + blockIdx.x;
  unsigned swz = (bid & 7) * (nwg >> 3) + (bid >> 3);
  const int bx = swz % gridDim.x, by = swz / gridDim.x;
  const int m0 = by * 128, n0 = bx * 128;
  const int tid = threadIdx.x;
  const int lane = tid & 63, wv = tid >> 6;
  const int lr = lane & 15, lg = lane >> 4;
  const int m_wave = (wv >> 1) * 64, n_wave = (wv & 1) * 64;

  f32x4 acc[4][4] = {};
  const int nk = K >> 6;
  const int srow = tid >> 3, skc = tid & 7;
  for (int ks = 0; ks < nk; ++ks) {
#pragma unroll
    for (int it = 0; it < 4; ++it) {
      int row = it * 32 + srow;
      unsigned ldsoff = (unsigned)(it * 4096 + (tid >> 6) * 1024);
      async16(A + (size_t)(m0 + row) * K + ks * 64 + skc * 8, (char*)As + ldsoff);
      async16(B + (size_t)(n0 + row) * K + ks * 64 + skc * 8, (char*)Bs + ldsoff);
    }
    __syncthreads();
#pragma unroll
    for (int kk = 0; kk < 64; kk += 32) {
      short8 a[4], b[4];
#pragma unroll
      for (int i = 0; i < 4; ++i)
        a[i] = *(const short8*)(As + (m_wave + i * 16 + lr) * 64 + kk + lg * 8);
#pragma unroll
      for (int i = 0; i < 4; ++i)
        b[i] = *(const short8*)(Bs + (n_wave + i * 16 + lr) * 64 + kk + lg * 8);
#pragma unroll
      for (int mi = 0; mi < 4; ++mi)
#pragma unroll
        for (int ni = 0; ni < 4; ++ni)
          acc[mi][ni] = __builtin_amdgcn_mfma_f32_16x16x32_bf16(a[mi], b[ni], acc[mi][ni], 0, 0, 0);
    }
    __syncthreads();
  }
#pragma unroll
  for (int ni = 0; ni < 4; ++ni) {
    int ng = n0 + n_wave + ni * 16 + lr;
    float bv = bias[ng];
    float* outp = P + (size_t)(ng >> 10) * pstride + (ng & 1023);
#pragma unroll
    for (int mi = 0; mi < 4; ++mi)
#pragma unroll
      for (int j = 0; j < 4; ++j) {
        int m = m0 + m_wave + mi * 16 + lg * 4 + j;
        outp[(size_t)m * 1024] = acc[mi][ni][j] + bv;
      }
  }
}

// ---------------- Phase B: persistent recurrent scan (R10-validated structure) ----------------
// 256 blocks x 512 threads (8 waves). Block: n-slice 16 cols (4 planes, K=1024 in LDS),
// m-slice 64 batch rows (R10 mapping: n=bid&63, m=bid>>6). Wave w: ph=w&1, kh=(w>>1)&1, mh=w>>2.
// Coherence (validated R8/R10): h stores write-through L3 (sc0 sc1), h loads cached,
// freshness via one ACQUIRE (L1/L2 inv) after detection. Stores drained by the
// pre-arrival vmcnt(0)+__syncthreads BEFORE the arrival add — do not reorder (R9 lesson).
// New in R12 — split-line barrier: arrivals are RELAXED adds on cnt (nobody polls it ->
// no line ping-pong, adds serialize at raw far-atomic rate); the last arriver
// (old == 64(t+1)-1, atomically claimed) publishes go = 64(t+1) on a separate line;
// everyone polls go (read-only between writes) with monotone < compare.
__global__ __launch_bounds__(512) void lstm_scan(
    int t0, int tc, const unsigned short* __restrict__ Wr,
    const float* __restrict__ P, size_t pstride,
    unsigned short* __restrict__ hbuf0, unsigned short* __restrict__ hbuf1,
    const float* __restrict__ cell, float* __restrict__ cbuf,
    float* __restrict__ out, unsigned* __restrict__ counter) {
  __shared__ unsigned short Wsm[4 * 16 * 1024];  // 128 KB
  __shared__ float fin[4][64][18];               // 18.4 KB exchange buffer

  const int tid = threadIdx.x;
  const int lane = tid & 63, w = tid >> 6;
  const int lr = lane & 15, lg = lane >> 4;
  const int ph = w & 1, kh = (w >> 1) & 1, mh = w >> 2;
  const int n0 = (blockIdx.x & 63) * 16, m0 = (blockIdx.x >> 6) * 64;
  unsigned* cnt = counter + (blockIdx.x >> 6) * 64;  // arrival line (never polled)
  unsigned* go = cnt + 32;                           // +128B: publish line (write-once/step)

  // stage Wr slice into LDS (once): row r = p*16+c holds W[p][n0+c][0..1023]
  for (int id = tid; id < 8192; id += 512) {
    int r = id >> 7, s = id & 127;
    int p = r >> 4, c = r & 15;
    short8 v = *(const short8*)(Wr + ((size_t)p * H_DIM + n0 + c) * H_DIM + s * 8);
    *(short8*)((char*)Wsm + r * 2048 + ((s ^ (c & 7)) << 4)) = v;
  }

  // per-thread epilogue ownership: 2 consecutive elements of the 64x16 tile
  const int em = tid >> 3, en = (tid & 7) * 2;
  const size_t cidx = (size_t)(m0 + em) * H_DIM + n0 + en;
  float creg0, creg1;
  {
    const float* csrc = (t0 == 0) ? cell : cbuf;
    creg0 = csrc[cidx];
    creg1 = csrc[cidx + 1];
  }
  __syncthreads();

  const int p0 = ph * 2;
  const int brow0 = (p0 * 16 + lr) * 2048, brow1 = brow0 + 16 * 2048;
  const int swz = (lr & 7) << 4;
  const size_t arow_off = (size_t)(m0 + mh * 32 + lr) * H_DIM + kh * 512 + lg * 8;

  // preload gate pre-acts for tmod=0 (P is a stable, read-only input)
  float pv[6][2];
  {
    const float* Pe = P + cidx;
#pragma unroll
    for (int p = 0; p < 6; ++p) {
      pv[p][0] = Pe[p * pstride];
      pv[p][1] = Pe[p * pstride + 1];
    }
  }

  for (int tmod = 0; tmod < tc; ++tmod) {
    const int t = t0 + tmod;
    const unsigned short* hin = (t & 1) ? hbuf1 : hbuf0;
    unsigned short* hout = (t & 1) ? hbuf0 : hbuf1;

    // batched cached A loads: full K-half for 2 rows (32 x 16B into regs).
    // Fresh because the barrier's ACQUIRE invalidated L1/L2; 8 same-group
    // blocks per XCD share the L3->L2 fill.
    short8 h0r[16], h1r[16];
    {
      const unsigned short* a0p = hin + arow_off;
      const unsigned short* a1p = a0p + 16 * H_DIM;
#pragma unroll
      for (int ki = 0; ki < 16; ++ki) {
        h0r[ki] = *(const short8*)(a0p + ki * 32);
        h1r[ki] = *(const short8*)(a1p + ki * 32);
      }
    }

    f32x4 acc[2][2] = {};  // [plane-in-pair][m-tile]
#pragma unroll
    for (int ki = 0; ki < 16; ++ki) {
      int sb = ((kh * 64 + ki * 4 + lg) << 4) ^ swz;
      short8 b0 = *(const short8*)((char*)Wsm + brow0 + sb);
      short8 b1 = *(const short8*)((char*)Wsm + brow1 + sb);
      acc[0][0] = __builtin_amdgcn_mfma_f32_16x16x32_bf16(h0r[ki], b0, acc[0][0], 0, 0, 0);
      acc[0][1] = __builtin_amdgcn_mfma_f32_16x16x32_bf16(h1r[ki], b0, acc[0][1], 0, 0, 0);
      acc[1][0] = __builtin_amdgcn_mfma_f32_16x16x32_bf16(h0r[ki], b1, acc[1][0], 0, 0, 0);
      acc[1][1] = __builtin_amdgcn_mfma_f32_16x16x32_bf16(h1r[ki], b1, acc[1][1], 0, 0, 0);
    }

    // prefetch next step's P into registers (overlaps LDS exchange + barrier)
    float pn[6][2] = {};
    if (tmod + 1 < tc) {
      const float* Pe = P + (size_t)(tmod + 1) * (B_DIM * H_DIM) + cidx;
#pragma unroll
      for (int p = 0; p < 6; ++p) {
        pn[p][0] = Pe[p * pstride];
        pn[p][1] = Pe[p * pstride + 1];
      }
    }

    // phase 1: kh=1 waves publish partials
    if (kh == 1) {
#pragma unroll
      for (int pp = 0; pp < 2; ++pp)
#pragma unroll
        for (int i = 0; i < 2; ++i)
#pragma unroll
          for (int j = 0; j < 4; ++j)
            fin[p0 + pp][mh * 32 + i * 16 + lg * 4 + j][lr] = acc[pp][i][j];
    }
    __syncthreads();

    // phase 2: kh=0 waves reduce and publish all 4 planes
    if (kh == 0) {
#pragma unroll
      for (int pp = 0; pp < 2; ++pp)
#pragma unroll
        for (int i = 0; i < 2; ++i)
#pragma unroll
          for (int j = 0; j < 4; ++j) {
            int mrow = mh * 32 + i * 16 + lg * 4 + j;
            fin[p0 + pp][mrow][lr] = acc[pp][i][j] + fin[p0 + pp][mrow][lr];
          }
    }
    __syncthreads();

    // phase 3: balanced epilogue — every thread handles its 2 elements
    {
      float r0a = fin[0][em][en], r0b = fin[0][em][en + 1];
      float r1a = fin[1][em][en], r1b = fin[1][em][en + 1];
      float r2a = fin[2][em][en], r2b = fin[2][em][en + 1];
      float r3a = fin[3][em][en], r3b = fin[3][em][en + 1];

      float ig0 = sigf(r0a + pv[0][0]), ig1 = sigf(r0b + pv[0][1]);
      float fg0 = sigf(r1a + pv[1][0]), fg1 = sigf(r1b + pv[1][1]);
      float og0 = sigf(r2a + pv[2][0]), og1 = sigf(r2b + pv[2][1]);
      float ct0 = tanhf_(r3a + pv[3][0]), ct1 = tanhf_(r3b + pv[3][1]);
      float lz0 = sigf(pv[4][0]) * tanhf_(pv[5][0]);
      float lz1 = sigf(pv[4][1]) * tanhf_(pv[5][1]);
      creg0 = fg0 * creg0 + ig0 * ct0 + lz0;
      creg1 = fg1 * creg1 + ig1 * ct1 + lz1;
      float hn0 = og0 * tanhf_(creg0);
      float hn1 = og1 * tanhf_(creg1);
      // h store: write-through to L3 (sc0 sc1) so no wbl2 fence is needed
      unsigned hv = (unsigned)f2bf(hn0) | ((unsigned)f2bf(hn1) << 16);
      asm volatile("global_store_dword %0, %1, off sc0 sc1"
                   :: "v"(hout + cidx), "v"(hv) : "memory");
      float* op = out + (size_t)t * (B_DIM * H_DIM) + cidx;
      __builtin_nontemporal_store(hn0, op);
      __builtin_nontemporal_store(hn1, op + 1);
    }

    // split-line barrier: drain stores, relaxed add on cnt (unpolled line),
    // last arriver publishes go, everyone polls go, one acquire (L1/L2 inv).
    asm volatile("s_waitcnt vmcnt(0)" ::: "memory");
    __syncthreads();
    if (tid == 0) {
      unsigned tgt = 64u * (unsigned)(t + 1);
      unsigned old = __hip_atomic_fetch_add(cnt, 1u, __ATOMIC_RELAXED, __HIP_MEMORY_SCOPE_AGENT);
      if (old == tgt - 1u)
        __hip_atomic_store(go, tgt, __ATOMIC_RELAXED, __HIP_MEMORY_SCOPE_AGENT);
      if (tmod + 1 < tc) {   // last step: arrival only (keeps absolute count valid)
        while (__hip_atomic_load(go, __ATOMIC_RELAXED, __HIP_MEMORY_SCOPE_AGENT) < tgt)
          __builtin_amdgcn_s_sleep(1);
        (void)__hip_atomic_load(cnt, __ATOMIC_ACQUIRE, __HIP_MEMORY_SCOPE_AGENT);
      }
    }
    __syncthreads();

    // rotate prefetched P
#pragma unroll
    for (int p = 0; p < 6; ++p) {
      pv[p][0] = pn[p][0];
      pv[p][1] = pn[p][1];
    }
  }

  // spill c for the next chunk (kernel-end release makes it visible)
  cbuf[cidx] = creg0;
  cbuf[cidx + 1] = creg1;
}

// ---------------- fallback fused step (round-1, verified) ----------------
__global__ __launch_bounds__(256) void lstm_step(
    int t, const float* __restrict__ x, const float* __restrict__ z,
    const unsigned short* __restrict__ Wr, const unsigned short* __restrict__ Wx,
    const unsigned short* __restrict__ Wz, const float* __restrict__ bias,
    const unsigned short* __restrict__ hin, unsigned short* __restrict__ hout,
    float* __restrict__ cbuf, float* __restrict__ out) {
  const int lane = threadIdx.x & 63;
  const int wv = threadIdx.x >> 6;
  const int m_base = blockIdx.y * 16;
  const int n_base = blockIdx.x * 64 + wv * 16;
  const int lr = lane & 15;
  const int lg = lane >> 4;
  const int n = n_base + lr;

  f32x4 acc[6];
#pragma unroll
  for (int p = 0; p < 6; ++p) {
    float bv = bias[p * H_DIM + n];
    acc[p] = (f32x4){bv, bv, bv, bv};
  }
  const unsigned short* hrow = hin + (size_t)(m_base + lr) * H_DIM + lg * 8;
  const float* xrow = x + ((size_t)t * B_DIM + m_base + lr) * E_DIM + lg * 8;
  const float* zrow = z + ((size_t)t * B_DIM + m_base + lr) * Z_DIM + lg * 8;
  const unsigned short* wrp = Wr + (size_t)n * H_DIM + lg * 8;
  const unsigned short* wxp = Wx + (size_t)n * E_DIM + lg * 8;
  const unsigned short* wzp = Wz + (size_t)n * Z_DIM + lg * 8;

#pragma unroll 2
  for (int kk = 0; kk < H_DIM; kk += 32) {
    short8 a = *(const short8*)(hrow + kk);
    short8 b0 = *(const short8*)(wrp + kk);
    short8 b1 = *(const short8*)(wrp + 1 * H_DIM * H_DIM + kk);
    short8 b2 = *(const short8*)(wrp + 2 * H_DIM * H_DIM + kk);
    short8 b3 = *(const short8*)(wrp + 3 * H_DIM * H_DIM + kk);
    acc[0] = __builtin_amdgcn_mfma_f32_16x16x32_bf16(a, b0, acc[0], 0, 0, 0);
    acc[1] = __builtin_amdgcn_mfma_f32_16x16x32_bf16(a, b1, acc[1], 0, 0, 0);
    acc[2] = __builtin_amdgcn_mfma_f32_16x16x32_bf16(a, b2, acc[2], 0, 0, 0);
    acc[3] = __builtin_amdgcn_mfma_f32_16x16x32_bf16(a, b3, acc[3], 0, 0, 0);
  }
#pragma unroll 2
  for (int kk = 0; kk < E_DIM; kk += 32) {
    f32x4 x0 = *(const f32x4*)(xrow + kk);
    f32x4 x1 = *(const f32x4*)(xrow + kk + 4);
    short8 a;
#pragma unroll
    for (int j = 0; j < 4; ++j) { a[j] = (short)f2bf(x0[j]); a[j + 4] = (short)f2bf(x1[j]); }
    short8 b0 = *(const short8*)(wxp + kk);
    short8 b1 = *(const short8*)(wxp + 1 * H_DIM * E_DIM + kk);
    short8 b2 = *(const short8*)(wxp + 2 * H_DIM * E_DIM + kk);
    short8 b3 = *(const short8*)(wxp + 3 * H_DIM * E_DIM + kk);
    acc[0] = __builtin_amdgcn_mfma_f32_16x16x32_bf16(a, b0, acc[0], 0, 0, 0);
    acc[1] = __builtin_amdgcn_mfma_f32_16x16x32_bf16(a, b1, acc[1], 0, 0, 0);
    acc[2] = __builtin_amdgcn_mfma_f32_16x16x32_bf16(a, b2, acc[2], 0, 0, 0);
    acc[3] = __builtin_amdgcn_mfma_f32_16x16x32_bf16(a, b3, acc[3], 0, 0, 0);
  }
#pragma unroll 2
  for (int kk = 0; kk < Z_DIM; kk += 32) {
    f32x4 z0 = *(const f32x4*)(zrow + kk);
    f32x4 z1 = *(const f32x4*)(zrow + kk + 4);
    short8 a;
#pragma unroll
    for (int j = 0; j < 4; ++j) { a[j] = (short)f2bf(z0[j]); a[j + 4] = (short)f2bf(z1[j]); }
    short8 b4 = *(const short8*)(wzp + kk);
    short8 b5 = *(const short8*)(wzp + 1 * H_DIM * Z_DIM + kk);
    acc[4] = __builtin_amdgcn_mfma_f32_16x16x32_bf16(a, b4, acc[4], 0, 0, 0);
    acc[5] = __builtin_amdgcn_mfma_f32_16x16x32_bf16(a, b5, acc[5], 0, 0, 0);
  }
#pragma unroll
  for (int j = 0; j < 4; ++j) {
    int b = m_base + lg * 4 + j;
    size_t idx = (size_t)b * H_DIM + n;
    float ig = sigf(acc[0][j]);
    float fg = sigf(acc[1][j]);
    float og = sigf(acc[2][j]);
    float ct = tanhf_(acc[3][j]);
    float lgate = sigf(acc[4][j]);
    float zh = tanhf_(acc[5][j]);
    float cn = fg * cbuf[idx] + ig * ct + lgate * zh;
    cbuf[idx] = cn;
    float hn = og * tanhf_(cn);
    hout[idx] = f2bf(hn);
    out[(size_t)t * (B_DIM * H_DIM) + idx] = hn;
  }
}

// ---------------- launch ----------------

extern "C" void kernel_launch(void* const* d_in, const int* in_sizes, int n_in,
                              void* d_out, int out_size, void* d_ws, size_t ws_size,
                              hipStream_t stream) {
  const float* x = (const float*)d_in[0];
  const float* z = (const float*)d_in[1];
  const float* hidden = (const float*)d_in[2];
  const float* cell = (const float*)d_in[3];
  const float* w_ih = (const float*)d_in[4];
  const float* w_oh = (const float*)d_in[5];
  const float* w_fh = (const float*)d_in[6];
  const float* w_ch = (const float*)d_in[7];
  const float* w_ix = (const float*)d_in[8];
  const float* w_ox = (const float*)d_in[9];
  const float* w_fx = (const float*)d_in[10];
  const float* w_cx = (const float*)d_in[11];
  const float* w_lx = (const float*)d_in[12];
  const float* w_zx = (const float*)d_in[13];
  const float* b_i = (const float*)d_in[14];
  const float* b_f = (const float*)d_in[15];
  const float* b_o = (const float*)d_in[16];
  const float* b_l = (const float*)d_in[17];
  const float* b_z = (const float*)d_in[18];
  const float* b_c = (const float*)d_in[19];

  char* ws = (char*)d_ws;
  unsigned short* Wr = (unsigned short*)(ws + 0);          //  8 MB [4][1024][1024]
  unsigned short* Wx = (unsigned short*)(ws + 8388608);    //  8 MB [4][1024][1024]
  unsigned short* Wz = (unsigned short*)(ws + 16777216);   //  2 MB [2][1024][512]
  float* bias = (float*)(ws + 18874368);                   // 24 KB [6][1024]
  unsigned short* h0 = (unsigned short*)(ws + 18898944);   // 512 KB
  unsigned short* h1 = (unsigned short*)(ws + 19423232);   // 512 KB
  float* cbuf = (float*)(ws + 19947520);                   //   1 MB
  unsigned* counter = (unsigned*)(ws + 20996096);          //   1 KB (cnt/go per m-group)
  float* out = (float*)d_out;

  const size_t FIXED = 20997120ULL;
  const size_t PER_T = 7077888ULL;  // xbf 512K + zbf 256K + P[6 planes] 6M
  int TC = 0;
  for (int c = 128; c >= 1; c >>= 1)
    if (FIXED + (size_t)c * PER_T <= ws_size) { TC = c; break; }

  // shared prep
  cvt_wr<<<dim3(4096, 4), 256, 0, stream>>>(w_ih, w_fh, w_oh, w_ch, Wr);
  transpose_k<<<dim3(32, 32, 4), dim3(32, 8), 0, stream>>>(w_ix, w_fx, w_ox, w_cx, Wx, E_DIM, H_DIM);
  transpose_k<<<dim3(32, 16, 2), dim3(32, 8), 0, stream>>>(w_lx, w_zx, w_lx, w_zx, Wz, Z_DIM, H_DIM);
  init_state<<<2074, 256, 0, stream>>>(hidden, cell, b_i, b_f, b_o, b_l, b_z, b_c, h0, cbuf, bias, counter);

  if (TC > 0) {
    unsigned short* xbf = (unsigned short*)(ws + FIXED);
    unsigned short* zbf = (unsigned short*)(ws + FIXED + (size_t)TC * 524288);
    float* P = (float*)(ws + FIXED + (size_t)TC * 786432);
    const size_t pstride = (size_t)TC * B_DIM * H_DIM;

    for (int t0 = 0; t0 < T_DIM; t0 += TC) {
      int nx4 = TC * B_DIM * E_DIM / 4;
      int nz4 = TC * B_DIM * Z_DIM / 4;
      cvt_bf16x4<<<(nx4 + 255) / 256, 256, 0, stream>>>(x + (size_t)t0 * B_DIM * E_DIM, xbf, nx4);
      cvt_bf16x4<<<(nz4 + 255) / 256, 256, 0, stream>>>(z + (size_t)t0 * B_DIM * Z_DIM, zbf, nz4);
      gemm_bt<<<dim3(32, TC * 2), 256, 0, stream>>>(xbf, Wx, bias, P, pstride, E_DIM);
      gemm_bt<<<dim3(16, TC * 2), 256, 0, stream>>>(zbf, Wz, bias + 4 * H_DIM, P + 4 * pstride, pstride, Z_DIM);
      lstm_scan<<<256, 512, 0, stream>>>(t0, TC, Wr, P, pstride, h0, h1, cell, cbuf, out, counter);
    }
  } else {
    // fallback: fully fused per-step path (round 1, verified)
    for (int t = 0; t < T_DIM; ++t) {
      const unsigned short* hin = (t & 1) ? h1 : h0;
      unsigned short* hout = (t & 1) ? h0 : h1;
      lstm_step<<<dim3(16, 16), 256, 0, stream>>>(t, x, z, Wr, Wx, Wz, bias, hin, hout, cbuf, out);
    }
  }
}